// Round 11
// baseline (233.408 us; speedup 1.0000x reference)
//
#include <hip/hip_runtime.h>
#include <hip/hip_fp16.h>
#include <stdint.h>
#include <stddef.h>

#define C_INC 320
#define KREAL 2880
#define KPAD  2944
#define OUT_F 384
#define RANK  32
#define HH    64
#define WW    64
#define NTOK  16384

typedef int   vi4 __attribute__((ext_vector_type(4)));
typedef float v4f __attribute__((ext_vector_type(4)));

// async global->LDS, 16B per lane; LDS dest is wave-uniform base + lane*16
static __device__ __forceinline__ void async16(const void* g, void* l) {
    __builtin_amdgcn_global_load_lds(
        (const __attribute__((address_space(1))) unsigned int*)g,
        (__attribute__((address_space(3))) unsigned int*)l, 16, 0, 0);
}

// ---------------- merged: per-pixel channel abs-max (blocks 0..511) +
//                  weight quantization (blocks 512..895) ----------------
__global__ __launch_bounds__(256) void k_pre(const float* __restrict__ x,
                                             float* __restrict__ mb2,
                                             const float* __restrict__ w,
                                             int8_t* __restrict__ qw,
                                             float* __restrict__ sw) {
    __shared__ float red[4];
    __shared__ float sval;
    int bx = blockIdx.x;
    if (bx < 512) {
        int cc = bx >> 6;                          // 0..7
        int p = (bx & 63) * 256 + threadIdx.x;     // 0..16383
        int n = p >> 12, hw = p & 4095;
        const float* base = x + ((size_t)(n * C_INC) + cc * 40) * 4096 + hw;
        float m = 0.f;
        #pragma unroll 4
        for (int c = 0; c < 40; ++c) m = fmaxf(m, fabsf(base[(size_t)c * 4096]));
        mb2[(size_t)cc * NTOK + p] = m;
    } else {
        int o = bx - 512;                          // 0..383
        const float* row = w + (size_t)o * KPAD;
        float m = 0.f;
        for (int k = threadIdx.x; k < KPAD; k += 256) m = fmaxf(m, fabsf(row[k]));
        #pragma unroll
        for (int off = 32; off > 0; off >>= 1) m = fmaxf(m, __shfl_down(m, off, 64));
        if ((threadIdx.x & 63) == 0) red[threadIdx.x >> 6] = m;
        __syncthreads();
        if (threadIdx.x == 0) {
            float mm = fmaxf(fmaxf(red[0], red[1]), fmaxf(red[2], red[3]));
            sval = fmaxf(mm / 7.0f, 1e-8f);
            sw[o] = sval;
        }
        __syncthreads();
        float s = sval;
        for (int k = threadIdx.x; k < KPAD; k += 256) {
            float q = rintf(row[k] / s);          // IEEE div + RNE, matches np
            q = fminf(fmaxf(q, -8.f), 7.f);
            qw[(size_t)o * KPAD + k] = (int8_t)q;
        }
    }
}

// ---------------- sx = max over 3x3 neighborhood of 8 planes / 7 ----------------
__global__ __launch_bounds__(256) void k_sx(const float* __restrict__ mb2,
                                            float* __restrict__ sx) {
    int p = blockIdx.x * 256 + threadIdx.x;
    int n = p >> 12, hw = p & 4095;
    int h = hw >> 6, w = hw & 63;
    float m = 0.f;
    #pragma unroll
    for (int cc = 0; cc < 8; ++cc) {
        const float* pl = mb2 + (size_t)cc * NTOK + (n << 12);
        #pragma unroll
        for (int di = -1; di <= 1; ++di)
            #pragma unroll
            for (int dj = -1; dj <= 1; ++dj) {
                int hh = h + di, ww = w + dj;
                if ((unsigned)hh < (unsigned)HH && (unsigned)ww < (unsigned)WW)
                    m = fmaxf(m, pl[(hh << 6) + ww]);
            }
    }
    sx[p] = fmaxf(m / 7.0f, 1e-8f);
}

// ---------------- fused im2col quantize + LoRA down-projection ----------------
// Templated on chunk count NCHT (16: proven R10 path; 32: doubles total waves
// 2048->4096 = 4/SIMD to hide latency — total wave count is the R10 ceiling).
// grid (32, NCHT), block 256: 8 image rows, 2 tokens/thread. NCHT=32 flushes
// with ushort stores (chunk k-base 90 B is not dword-aligned).
template <int NCHT>
__global__ __launch_bounds__(256) void k_fused(const float* __restrict__ x,
                                               const float* __restrict__ pd,
                                               const float* __restrict__ sx,
                                               int8_t* __restrict__ qx,
                                               __half* __restrict__ rpart) {
    constexpr int CCHT = 320 / NCHT;               // 20 or 10
    constexpr int KB   = CCHT * 9;                 // chunk k-bytes: 180 or 90
    constexpr int P0   = (NCHT == 16) ? 8 : 4;     // phase sizes {P0,P0,P2}
    constexpr int P2   = (NCHT == 16) ? 4 : 2;
    constexpr int QSTR = P0 * 9 + 4;               // 76 or 40
    __shared__ float  pdl[P0 * 9 * RANK];
    __shared__ int8_t qbuf[512 * QSTR];
    const int pstart[4] = {0, P0, 2 * P0, 2 * P0 + P2};

    int tid = threadIdx.x;                 // 0..255
    int rg = blockIdx.x;                   // 0..31
    int cc = blockIdx.y;                   // 0..NCHT-1
    int n = rg >> 3, h8 = rg & 7;
    int wid = tid >> 6, lane = tid & 63;
    int h0 = h8 * 8;
    int ha = h0 + wid, hb = h0 + 4 + wid;
    int c0 = cc * CCHT;

    int ta = (n << 12) + (ha << 6) + lane;
    int tb = (n << 12) + (hb << 6) + lane;
    float inva = 1.0f / sx[ta];
    float invb = 1.0f / sx[tb];
    const float* xrowa = x + ((size_t)(n * C_INC) + c0) * 4096 + (ha << 6) + lane;
    const float* xrowb = x + ((size_t)(n * C_INC) + c0) * 4096 + (hb << 6) + lane;
    bool hok0a = (ha > 0), hok2a = (ha < 63);
    bool hok0b = (hb > 0), hok2b = (hb < 63);
    bool wok0 = (lane > 0), wok2 = (lane < 63);
    int bt = (n << 12) + (h8 << 9);        // block's first token (8 rows)
    int qra = wid * 64 + lane;
    int qrb = 256 + wid * 64 + lane;

    v4f acca[8], accb[8];
    #pragma unroll
    for (int j = 0; j < 8; ++j) { acca[j] = (v4f)0.f; accb[j] = (v4f)0.f; }

    for (int ph = 0; ph < 3; ++ph) {
        int ps = pstart[ph], pch = pstart[ph + 1] - ps;
        __syncthreads();   // prior phase's pdl reads + qbuf writes complete
        if (ph > 0) {      // flush previous phase: P0 ch = 18 units/row
            int ub = (ph - 1) * 18;        // unit offset (dword or ushort)
            if constexpr (NCHT == 16) {
                for (int i = tid; i < 512 * 18; i += 256) {
                    int row = i / 18, col = i - row * 18;
                    *(unsigned int*)&qx[(size_t)(bt + row) * KPAD + cc * KB + (ub + col) * 4] =
                        *(unsigned int*)&qbuf[row * QSTR + col * 4];
                }
            } else {
                for (int i = tid; i < 512 * 18; i += 256) {
                    int row = i / 18, col = i - row * 18;
                    *(unsigned short*)&qx[(size_t)(bt + row) * KPAD + cc * KB + (ub + col) * 2] =
                        *(unsigned short*)&qbuf[row * QSTR + col * 2];
                }
            }
        }
        for (int i = tid; i < pch * 9 * RANK; i += 256)
            pdl[i] = pd[((size_t)(c0 + ps) * 9) * RANK + i];
        __syncthreads();   // pdl ready, flush done

        const float* xca = xrowa + (size_t)ps * 4096;
        const float* xcb = xrowb + (size_t)ps * 4096;
        float r0a = hok0a ? xca[-64] : 0.f, r1a = xca[0], r2a = hok2a ? xca[64] : 0.f;
        float r0b = hok0b ? xcb[-64] : 0.f, r1b = xcb[0], r2b = hok2b ? xcb[64] : 0.f;

        for (int cl = 0; cl < pch; ++cl) {
            float p0a = 0.f, p1a = 0.f, p2a = 0.f, p0b = 0.f, p1b = 0.f, p2b = 0.f;
            if (cl + 1 < pch) {
                const float* xna = xrowa + (size_t)(ps + cl + 1) * 4096;
                const float* xnb = xrowb + (size_t)(ps + cl + 1) * 4096;
                p0a = hok0a ? xna[-64] : 0.f; p1a = xna[0]; p2a = hok2a ? xna[64] : 0.f;
                p0b = hok0b ? xnb[-64] : 0.f; p1b = xnb[0]; p2b = hok2b ? xnb[64] : 0.f;
            }
            float va[9], vb[9];
            {
                float u0 = __shfl_up(r0a, 1, 64), d0 = __shfl_down(r0a, 1, 64);
                float u1 = __shfl_up(r1a, 1, 64), d1 = __shfl_down(r1a, 1, 64);
                float u2 = __shfl_up(r2a, 1, 64), d2 = __shfl_down(r2a, 1, 64);
                va[0] = wok0 ? u0 : 0.f; va[1] = r0a; va[2] = wok2 ? d0 : 0.f;
                va[3] = wok0 ? u1 : 0.f; va[4] = r1a; va[5] = wok2 ? d1 : 0.f;
                va[6] = wok0 ? u2 : 0.f; va[7] = r2a; va[8] = wok2 ? d2 : 0.f;
            }
            {
                float u0 = __shfl_up(r0b, 1, 64), d0 = __shfl_down(r0b, 1, 64);
                float u1 = __shfl_up(r1b, 1, 64), d1 = __shfl_down(r1b, 1, 64);
                float u2 = __shfl_up(r2b, 1, 64), d2 = __shfl_down(r2b, 1, 64);
                vb[0] = wok0 ? u0 : 0.f; vb[1] = r0b; vb[2] = wok2 ? d0 : 0.f;
                vb[3] = wok0 ? u1 : 0.f; vb[4] = r1b; vb[5] = wok2 ? d1 : 0.f;
                vb[6] = wok0 ? u2 : 0.f; vb[7] = r2b; vb[8] = wok2 ? d2 : 0.f;
            }
            #pragma unroll
            for (int u = 0; u < 9; ++u) {
                float qa = rintf(va[u] * inva);
                qa = fminf(fmaxf(qa, -8.f), 7.f);
                qbuf[qra * QSTR + cl * 9 + u] = (int8_t)qa;
                float qb = rintf(vb[u] * invb);
                qb = fminf(fmaxf(qb, -8.f), 7.f);
                qbuf[qrb * QSTR + cl * 9 + u] = (int8_t)qb;
                const v4f* p4 = (const v4f*)&pdl[(cl * 9 + u) * RANK];
                v4f va4; va4[0] = va[u]; va4[1] = va[u]; va4[2] = va[u]; va4[3] = va[u];
                v4f vb4; vb4[0] = vb[u]; vb4[1] = vb[u]; vb4[2] = vb[u]; vb4[3] = vb[u];
                #pragma unroll
                for (int jj = 0; jj < 8; ++jj) {
                    v4f pv = p4[jj];
                    acca[jj] += pv * va4;   // v_pk_fma_f32 x2
                    accb[jj] += pv * vb4;
                }
            }
            r0a = p0a; r1a = p1a; r2a = p2a;
            r0b = p0b; r1b = p1b; r2b = p2b;
        }
    }

    // store rpart partials as fp16 (both tokens)
    {
        union { __half hh[RANK]; uint4 u4[4]; } pk;
        #pragma unroll
        for (int jj = 0; jj < 8; ++jj) {
            pk.hh[4 * jj + 0] = __float2half_rn(acca[jj][0]);
            pk.hh[4 * jj + 1] = __float2half_rn(acca[jj][1]);
            pk.hh[4 * jj + 2] = __float2half_rn(acca[jj][2]);
            pk.hh[4 * jj + 3] = __float2half_rn(acca[jj][3]);
        }
        uint4* rp = (uint4*)(rpart + ((size_t)cc * NTOK + ta) * RANK);
        rp[0] = pk.u4[0]; rp[1] = pk.u4[1]; rp[2] = pk.u4[2]; rp[3] = pk.u4[3];
        #pragma unroll
        for (int jj = 0; jj < 8; ++jj) {
            pk.hh[4 * jj + 0] = __float2half_rn(accb[jj][0]);
            pk.hh[4 * jj + 1] = __float2half_rn(accb[jj][1]);
            pk.hh[4 * jj + 2] = __float2half_rn(accb[jj][2]);
            pk.hh[4 * jj + 3] = __float2half_rn(accb[jj][3]);
        }
        rp = (uint4*)(rpart + ((size_t)cc * NTOK + tb) * RANK);
        rp[0] = pk.u4[0]; rp[1] = pk.u4[1]; rp[2] = pk.u4[2]; rp[3] = pk.u4[3];
    }

    // flush final phase: P2 ch = 9 units (+pad to KPAD on last chunk)
    __syncthreads();
    if constexpr (NCHT == 16) {
        if (cc == NCHT - 1) {
            for (int i = tid; i < 512 * 25; i += 256) {
                int row = i / 25, col = i - row * 25;
                unsigned int vdw = (col < 9) ? *(unsigned int*)&qbuf[row * QSTR + col * 4] : 0u;
                *(unsigned int*)&qx[(size_t)(bt + row) * KPAD + cc * KB + (36 + col) * 4] = vdw;
            }
        } else {
            for (int i = tid; i < 512 * 9; i += 256) {
                int row = i / 9, col = i - row * 9;
                *(unsigned int*)&qx[(size_t)(bt + row) * KPAD + cc * KB + (36 + col) * 4] =
                    *(unsigned int*)&qbuf[row * QSTR + col * 4];
            }
        }
    } else {
        if (cc == NCHT - 1) {
            for (int i = tid; i < 512 * 41; i += 256) {
                int row = i / 41, col = i - row * 41;
                unsigned short vus = (col < 9) ? *(unsigned short*)&qbuf[row * QSTR + col * 2]
                                               : (unsigned short)0;
                *(unsigned short*)&qx[(size_t)(bt + row) * KPAD + cc * KB + (36 + col) * 2] = vus;
            }
        } else {
            for (int i = tid; i < 512 * 9; i += 256) {
                int row = i / 9, col = i - row * 9;
                *(unsigned short*)&qx[(size_t)(bt + row) * KPAD + cc * KB + (36 + col) * 2] =
                    *(unsigned short*)&qbuf[row * QSTR + col * 2];
            }
        }
    }
}

// ---------------- int8 MFMA GEMM: 64x128 tiles, double-buffered async staging ----------------
__global__ __launch_bounds__(256) void k_gemm(const int8_t* __restrict__ qx,
                                              const int8_t* __restrict__ qw,
                                              const float* __restrict__ sx,
                                              const float* __restrict__ sw,
                                              float* __restrict__ out) {
    __shared__ int8_t lsA[2][64 * 64];
    __shared__ int8_t lsB[2][128 * 64];
    int tid = threadIdx.x;
    int n0 = blockIdx.x * 128;
    int m0 = blockIdx.y * 64;
    int wid = tid >> 6, lane = tid & 63;
    int wr = wid >> 1, wc = wid & 1;
    int lg = lane >> 4, lr = lane & 15;

    const int8_t* gA  = qx + (size_t)(m0 + wid * 16 + (lane >> 2)) * KPAD + (lane & 3) * 16;
    const int8_t* gB0 = qw + (size_t)(n0 + wid * 16 + (lane >> 2)) * KPAD + (lane & 3) * 16;
    const int8_t* gB1 = gB0 + (size_t)64 * KPAD;
    int lofs = wid * 1024;

    vi4 acc[2][4];
    #pragma unroll
    for (int i = 0; i < 2; ++i)
        #pragma unroll
        for (int j = 0; j < 4; ++j) acc[i][j] = (vi4)0;

    async16(gA, &lsA[0][lofs]);
    async16(gB0, &lsB[0][lofs]);
    async16(gB1, &lsB[0][4096 + lofs]);
    __syncthreads();

    int cur = 0;
    for (int kk = 64; kk < KPAD; kk += 64) {
        int nxt = cur ^ 1;
        async16(gA + kk, &lsA[nxt][lofs]);
        async16(gB0 + kk, &lsB[nxt][lofs]);
        async16(gB1 + kk, &lsB[nxt][4096 + lofs]);
        vi4 af[2], bf[4];
        #pragma unroll
        for (int mi = 0; mi < 2; ++mi)
            af[mi] = *(vi4*)&lsA[cur][(wr * 32 + mi * 16 + lr) * 64 + lg * 16];
        #pragma unroll
        for (int ni = 0; ni < 4; ++ni)
            bf[ni] = *(vi4*)&lsB[cur][(wc * 64 + ni * 16 + lr) * 64 + lg * 16];
        #pragma unroll
        for (int mi = 0; mi < 2; ++mi)
            #pragma unroll
            for (int ni = 0; ni < 4; ++ni)
                acc[mi][ni] = __builtin_amdgcn_mfma_i32_16x16x64_i8(af[mi], bf[ni], acc[mi][ni], 0, 0, 0);
        __syncthreads();
        cur = nxt;
    }
    {
        vi4 af[2], bf[4];
        #pragma unroll
        for (int mi = 0; mi < 2; ++mi)
            af[mi] = *(vi4*)&lsA[cur][(wr * 32 + mi * 16 + lr) * 64 + lg * 16];
        #pragma unroll
        for (int ni = 0; ni < 4; ++ni)
            bf[ni] = *(vi4*)&lsB[cur][(wc * 64 + ni * 16 + lr) * 64 + lg * 16];
        #pragma unroll
        for (int mi = 0; mi < 2; ++mi)
            #pragma unroll
            for (int ni = 0; ni < 4; ++ni)
                acc[mi][ni] = __builtin_amdgcn_mfma_i32_16x16x64_i8(af[mi], bf[ni], acc[mi][ni], 0, 0, 0);
    }

    float swv[4];
    #pragma unroll
    for (int ni = 0; ni < 4; ++ni) swv[ni] = sw[n0 + wc * 64 + ni * 16 + lr];
    #pragma unroll
    for (int mi = 0; mi < 2; ++mi) {
        int rbase = m0 + wr * 32 + mi * 16 + lg * 4;
        #pragma unroll
        for (int r = 0; r < 4; ++r) {
            int row = rbase + r;
            float sxv = sx[row];
            #pragma unroll
            for (int ni = 0; ni < 4; ++ni) {
                int col = n0 + wc * 64 + ni * 16 + lr;
                out[(size_t)row * OUT_F + col] = ((float)acc[mi][ni][r] * sxv) * swv[ni];
            }
        }
    }
}

// ---------------- epilogue: out += (sum_cc rpart) @ up + bias ----------------
template <int NCHT>
__global__ __launch_bounds__(384) void k_epi(float* __restrict__ out,
                                             const __half* __restrict__ rpart,
                                             const float* __restrict__ up,
                                             const float* __restrict__ bias) {
    __shared__ float rs[32][RANK];        // 4 KB
    int tid = threadIdx.x;                // 0..383
    int o = tid;
    float uc[RANK];
    #pragma unroll
    for (int j = 0; j < RANK; ++j) uc[j] = up[(size_t)j * OUT_F + o];
    float b = bias[o];
    int t0 = blockIdx.x * 32;
    for (int i = tid; i < 32 * RANK; i += 384) {
        int tt = i >> 5, j = i & 31;
        float s = 0.f;
        #pragma unroll
        for (int cc = 0; cc < NCHT; ++cc)
            s += __half2float(rpart[((size_t)cc * NTOK + t0 + tt) * RANK + j]);
        rs[tt][j] = s;
    }
    __syncthreads();
    for (int tt = 0; tt < 32; ++tt) {
        int t = t0 + tt;
        float a = out[(size_t)t * OUT_F + o];
        float l = 0.f;
        const v4f* rv = (const v4f*)&rs[tt][0];
        #pragma unroll
        for (int j4 = 0; j4 < 8; ++j4) {
            v4f r4 = rv[j4];
            l = fmaf(r4[0], uc[4 * j4 + 0], l);
            l = fmaf(r4[1], uc[4 * j4 + 1], l);
            l = fmaf(r4[2], uc[4 * j4 + 2], l);
            l = fmaf(r4[3], uc[4 * j4 + 3], l);
        }
        out[(size_t)t * OUT_F + o] = a + l + b;
    }
}

extern "C" void kernel_launch(void* const* d_in, const int* in_sizes, int n_in,
                              void* d_out, int out_size, void* d_ws, size_t ws_size,
                              hipStream_t stream) {
    const float* x    = (const float*)d_in[0];
    const float* w    = (const float*)d_in[1];
    const float* pd   = (const float*)d_in[2];
    const float* pu   = (const float*)d_in[3];
    const float* bias = (const float*)d_in[4];
    float* out = (float*)d_out;

    char* ws = (char*)d_ws;
    int8_t* qw    = (int8_t*)(ws + 0);           // 1,130,496
    float*  sw    = (float*) (ws + 1130496);     // 1,536
    float*  mb2   = (float*) (ws + 1132032);     // 524,288
    float*  sx    = (float*) (ws + 1656320);     // 65,536
    int8_t* qx    = (int8_t*)(ws + 1721856);     // 48,234,496
    __half* rpart = (__half*)(ws + 49956352);    // 16 or 32 planes x 16384x32 fp16

    // NCH=32 doubles wave-level parallelism in k_fused but needs 83.5 MB of ws.
    // Branch on ws_size (deterministic every call -> graph-safe).
    bool big = ws_size >= (size_t)49956352 + (size_t)32 * NTOK * RANK * 2;

    hipLaunchKernelGGL(k_pre, dim3(896), dim3(256), 0, stream, x, mb2, w, qw, sw);
    hipLaunchKernelGGL(k_sx,  dim3(64),  dim3(256), 0, stream, mb2, sx);
    if (big) {
        hipLaunchKernelGGL((k_fused<32>), dim3(32, 32), dim3(256), 0, stream, x, pd, sx, qx, rpart);
    } else {
        hipLaunchKernelGGL((k_fused<16>), dim3(32, 16), dim3(256), 0, stream, x, pd, sx, qx, rpart);
    }
    hipLaunchKernelGGL(k_gemm, dim3(3, 256), dim3(256), 0, stream, qx, qw, sx, sw, out);
    if (big) {
        hipLaunchKernelGGL((k_epi<32>), dim3(512), dim3(384), 0, stream, out, rpart, pu, bias);
    } else {
        hipLaunchKernelGGL((k_epi<16>), dim3(512), dim3(384), 0, stream, out, rpart, pu, bias);
    }
}